// Round 5
// baseline (49.964 us; speedup 1.0000x reference)
//
#include <hip/hip_runtime.h>
#include <stdint.h>

#define N_IMG 16
#define H_DIM 512
#define W_DIM 512
#define PADR 15
#define BAND 8                  // output rows per mega block
#define HALO (BAND + 2 * PADR)  // 38 staged bitmap rows
#define WPR 18                  // 32-bit words per bitmap row: 1 pad + 16 data + 1 pad
#define NBANDS (H_DIM / BAND)   // 64
#define WROW (W_DIM / 32)       // 16 data words per row
#define NBLK (NBANDS * N_IMG)   // 1024 mega blocks

// ws layout (POISONED by the harness every iteration -> nothing may rely on
// prior ws contents; every word is write-before-read within one launch):
//   acc @ 0      : float aIn[32], aUn[32], aBce[16]; uint32 cnt (float idx 80)
//   bm  @ 32 KiB : uint32 bm[N][512][16]  (bit c&31 of word c>>5 = target==1)
// acc is zeroed by bitmap_kernel block 0; mega_kernel (stream-ordered after)
// then atomically accumulates into it. Kernel-boundary coherence makes the
// plain zero-stores visible to mega's device-scope atomics.

// ---------------------------------------------------------------------------
// Stage 1: target -> bit-plane. int4 x2 per thread (8 elems), words assembled
// with 2 shfl_xor OR-merges. 2048 blocks x 256 threads; ~HBM-bound (16.8 MB).
// Block 0 additionally zeroes the accumulator slab for this launch.
// ---------------------------------------------------------------------------
__global__ __launch_bounds__(256) void bitmap_kernel(const int4* __restrict__ tg4,
                                                     uint32_t* __restrict__ bm,
                                                     float* __restrict__ acc) {
    const int tid = threadIdx.x;
    if (blockIdx.x == 0 && tid < 81) acc[tid] = 0.0f;   // includes cnt (bit-zero)
    const size_t t = (size_t)blockIdx.x * 256 + tid;    // global thread, 8 ints each
    const int4 a = tg4[t * 2];
    const int4 b = tg4[t * 2 + 1];
    uint32_t by = (uint32_t)(a.x == 1) | ((uint32_t)(a.y == 1) << 1) |
                  ((uint32_t)(a.z == 1) << 2) | ((uint32_t)(a.w == 1) << 3) |
                  ((uint32_t)(b.x == 1) << 4) | ((uint32_t)(b.y == 1) << 5) |
                  ((uint32_t)(b.z == 1) << 6) | ((uint32_t)(b.w == 1) << 7);
    uint32_t w = by << (8 * (tid & 3));
    w |= __shfl_xor(w, 1);
    w |= __shfl_xor(w, 2);
    if ((tid & 3) == 0) bm[t >> 2] = w;
}

// ---------------------------------------------------------------------------
// Stage 2: fused 31x31 box-sum (popcount over bit-plane) + elementwise loss
// + last-block-done global finalize (replaces a third kernel).
// Block = 512 threads (one per col) x 8 output rows. 1024 blocks -> 4/CU.
// ---------------------------------------------------------------------------
__global__ __launch_bounds__(512, 8) void mega_kernel(const uint32_t* __restrict__ bm,
                                                      const float* __restrict__ pred,
                                                      float* __restrict__ acc,
                                                      float* __restrict__ out) {
    __shared__ uint32_t B[HALO][WPR];
    __shared__ float red[8 * 5];
    __shared__ int lastFlag;
    const int tid = threadIdx.x;                 // = col
    const int band = blockIdx.x;                 // 0..63
    const int n = blockIdx.y;
    const int r0 = band * BAND;
    const int col = tid;

    // ---- bitmap halo staging: 38 rows x 16 words = 608 loads, 2 per thread ----
    const uint32_t* __restrict__ bmn = bm + (size_t)n * H_DIM * WROW;
    const int hr0 = tid >> 4, wi = tid & 15;     // task 0: t = tid
    const int ra = r0 - PADR + hr0;
    uint32_t w0 = 0, w1 = 0;
    if (ra >= 0 && ra < H_DIM) w0 = bmn[ra * WROW + wi];
    const int hr1 = hr0 + 32;                    // task 1: t = tid + 512 (tid < 96)
    const int rb = r0 - PADR + hr1;
    if (tid < 96 && rb >= 0 && rb < H_DIM) w1 = bmn[rb * WROW + wi];

    // ---- pred loads issued early: outstanding across staging+barrier+popcounts
    const size_t img = (size_t)n * H_DIM * W_DIM;
    const float* __restrict__ p0 = pred + img * 2 + (size_t)r0 * W_DIM + col;
    const float* __restrict__ p1 = p0 + (size_t)H_DIM * W_DIM;
    float x0[BAND], x1[BAND];
#pragma unroll
    for (int rr = 0; rr < BAND; ++rr) {
        x0[rr] = p0[rr * W_DIM];
        x1[rr] = p1[rr * W_DIM];
    }

    // ---- LDS writes (wait only on bitmap loads; pred stays in flight) ----
    if (tid < 2 * HALO) B[tid >> 1][(tid & 1) ? (WPR - 1) : 0] = 0u;
    B[hr0][1 + wi] = w0;
    if (tid < 96) B[hr1][1 + wi] = w1;
    __syncthreads();

    // ---- 31-bit window popcount helper (near-broadcast LDS reads) ----
    const int b = col + (32 - PADR);             // window start bit (word 0 = pad)
    const int q = b >> 5, s = b & 31;
    auto wpop = [&](int i) -> uint32_t {
        const uint32_t lo = B[i][q];
        const uint32_t hi = B[i][q + 1];
        return (uint32_t)((((uint64_t)hi << 32) | lo) >> s) & 0x7FFFFFFFu;
    };

    // ---- initial vertical window (halo rows 0..30) + center-bit mask ----
    uint32_t run = 0, mbits = 0;
#pragma unroll
    for (int i = 0; i < 31; ++i) {
        const uint32_t val = wpop(i);
        run += (uint32_t)__popc(val);
        if (i >= PADR && i < PADR + BAND)
            mbits |= ((val >> PADR) & 1u) << (i - PADR);  // center bit = window bit 15
    }

    // ---- loss math ----
    const int cntw = min(col + PADR, W_DIM - 1) - max(col - PADR, 0) + 1;
    const float inv961 = 1.0f / 961.0f;
    float bce = 0.f, in0 = 0.f, in1 = 0.f, un0 = 0.f, un1 = 0.f;

#pragma unroll
    for (int rr = 0; rr < BAND; ++rr) {
        const int r = r0 + rr;
        const int cnth = min(r + PADR, H_DIM - 1) - max(r - PADR, 0) + 1;
        const float cnt = (float)(cnth * cntw);
        const float m1 = (float)((mbits >> rr) & 1u);
        const float m0 = 1.0f - m1;
        const float V = (float)run;
        const float box1 = V * inv961;
        const float box0 = (cnt - V) * inv961;
        const float w1f = 1.0f + 5.0f * fabsf(box1 - m1);
        const float w0f = 1.0f + 5.0f * fabsf(box0 - m0);
        {   // channel 0
            const float x = x0[rr];
            const float t = __expf(-fabsf(x));
            const float inv = 1.0f / (1.0f + t);
            const float p = (x >= 0.f) ? inv : t * inv;
            bce += fmaxf(x, 0.f) - x * m0 + __logf(1.0f + t);
            in0 += p * m0 * w0f;
            un0 += (p + m0) * w0f;
        }
        {   // channel 1
            const float x = x1[rr];
            const float t = __expf(-fabsf(x));
            const float inv = 1.0f / (1.0f + t);
            const float p = (x >= 0.f) ? inv : t * inv;
            bce += fmaxf(x, 0.f) - x * m1 + __logf(1.0f + t);
            in1 += p * m1 * w1f;
            un1 += (p + m1) * w1f;
        }
        if (rr < BAND - 1)   // slide vertical window: recompute from LDS (no h[])
            run += (uint32_t)__popc(wpop(rr + 31)) - (uint32_t)__popc(wpop(rr));
    }

    // ---- block reduction: 5 values ----
    const int lane = tid & 63, wv = tid >> 6;
    float v[5] = {bce, in0, in1, un0, un1};
#pragma unroll
    for (int k = 0; k < 5; ++k)
#pragma unroll
        for (int off = 32; off > 0; off >>= 1)
            v[k] += __shfl_down(v[k], off);
    if (lane == 0)
#pragma unroll
        for (int k = 0; k < 5; ++k) red[wv * 5 + k] = v[k];
    __syncthreads();

    // ---- atomic accumulation + last-block-done finalize ----
    float* aIn = acc;            // [32]  (n,c)
    float* aUn = acc + 32;       // [32]
    float* aBce = acc + 64;      // [16]  per image
    uint32_t* cnt = (uint32_t*)(acc + 80);
    if (tid == 0) {
        float s2[5];
#pragma unroll
        for (int k = 0; k < 5; ++k) {
            s2[k] = red[k];
            for (int w2 = 1; w2 < 8; ++w2) s2[k] += red[w2 * 5 + k];
        }
        atomicAdd(&aBce[n], s2[0]);
        atomicAdd(&aIn[n * 2 + 0], s2[1]);
        atomicAdd(&aIn[n * 2 + 1], s2[2]);
        atomicAdd(&aUn[n * 2 + 0], s2[3]);
        atomicAdd(&aUn[n * 2 + 1], s2[4]);
        __threadfence();
        lastFlag = (atomicAdd(cnt, 1u) == NBLK - 1);
    }
    __syncthreads();
    if (lastFlag) {                       // block-uniform (lastFlag is shared)
        __threadfence();
        float sw = 0.f, sb = 0.f;
        if (tid < 32) {
            const float vin = __hip_atomic_load(&aIn[tid], __ATOMIC_RELAXED,
                                                __HIP_MEMORY_SCOPE_AGENT);
            const float vun = __hip_atomic_load(&aUn[tid], __ATOMIC_RELAXED,
                                                __HIP_MEMORY_SCOPE_AGENT);
            sw = 1.0f - (vin + 1.0f) / (vun - vin + 1.0f);
        }
        if (tid < 16)
            sb = __hip_atomic_load(&aBce[tid], __ATOMIC_RELAXED,
                                   __HIP_MEMORY_SCOPE_AGENT);
        if (tid < 64) {
#pragma unroll
            for (int off = 32; off > 0; off >>= 1) {
                sw += __shfl_down(sw, off);
                sb += __shfl_down(sb, off);
            }
            if (tid == 0)
                out[0] = sb / 8388608.0f + sw * (1.0f / 32.0f);  // 16*2*512*512 ; 32
        }
    }
}

extern "C" void kernel_launch(void* const* d_in, const int* in_sizes, int n_in,
                              void* d_out, int out_size, void* d_ws, size_t ws_size,
                              hipStream_t stream) {
    const float* pred = (const float*)d_in[0];
    const int* target = (const int*)d_in[1];
    float* acc = (float*)d_ws;
    uint32_t* bm = (uint32_t*)((char*)d_ws + 32768);

    bitmap_kernel<<<2048, 256, 0, stream>>>((const int4*)target, bm, acc);
    dim3 grid(NBANDS, N_IMG);
    mega_kernel<<<grid, 512, 0, stream>>>(bm, pred, acc, (float*)d_out);
}

// Round 6
// 26.805 us; speedup vs baseline: 1.8640x; 1.8640x over previous
//
#include <hip/hip_runtime.h>
#include <stdint.h>

#define N_IMG 16
#define H_DIM 512
#define W_DIM 512
#define PADR 15
#define BAND 8                  // output rows per mega block
#define HALO (BAND + 2 * PADR)  // 38 staged bitmap rows
#define WPR 18                  // 32-bit words per bitmap row: 1 pad + 16 data + 1 pad
#define NBANDS (H_DIM / BAND)   // 64
#define WROW (W_DIM / 32)       // 16 data words per row

// ws layout (poison-safe: every word written before read, every launch):
//   part @ 0      : 1024 blocks * 5 f32  [bce,in0,in1,un0,un1]
//   bm   @ 32 KiB : uint32 bm[N][512][16]  (bit c&31 of word c>>5 = target==1)

// ---------------------------------------------------------------------------
// Stage 1: target -> bit-plane. int4 x2 per thread (8 elems), words assembled
// with 2 shfl_xor OR-merges. 2048 blocks x 256 threads; ~HBM-bound (16.8 MB).
// ---------------------------------------------------------------------------
__global__ __launch_bounds__(256) void bitmap_kernel(const int4* __restrict__ tg4,
                                                     uint32_t* __restrict__ bm) {
    const int tid = threadIdx.x;
    const size_t t = (size_t)blockIdx.x * 256 + tid;   // global thread, 8 ints each
    const int4 a = tg4[t * 2];
    const int4 b = tg4[t * 2 + 1];
    uint32_t by = (uint32_t)(a.x == 1) | ((uint32_t)(a.y == 1) << 1) |
                  ((uint32_t)(a.z == 1) << 2) | ((uint32_t)(a.w == 1) << 3) |
                  ((uint32_t)(b.x == 1) << 4) | ((uint32_t)(b.y == 1) << 5) |
                  ((uint32_t)(b.z == 1) << 6) | ((uint32_t)(b.w == 1) << 7);
    uint32_t w = by << (8 * (tid & 3));
    w |= __shfl_xor(w, 1);
    w |= __shfl_xor(w, 2);
    if ((tid & 3) == 0) bm[t >> 2] = w;
}

// ---------------------------------------------------------------------------
// Stage 2: fused 31x31 box-sum (popcount over bit-plane) + elementwise loss.
// Block = 512 threads (one per col) x 8 output rows. 1024 blocks -> 4/CU,
// 32 waves/CU. Pred values are register-pinned (asm keep-alive) so the
// allocator cannot sink the 16 pred loads into the loss loop (R5 lesson:
// VGPR=32 codegen serialized them -> 44 us).
// ---------------------------------------------------------------------------
__global__ __launch_bounds__(512, 8) void mega_kernel(const uint32_t* __restrict__ bm,
                                                      const float* __restrict__ pred,
                                                      float* __restrict__ part) {
    __shared__ uint32_t B[HALO][WPR];
    const int tid = threadIdx.x;                 // = col
    const int band = blockIdx.x;                 // 0..63
    const int n = blockIdx.y;
    const int r0 = band * BAND;
    const int col = tid;

    // ---- bitmap halo staging: 38 rows x 16 words = 608 loads, 2 per thread ----
    const uint32_t* __restrict__ bmn = bm + (size_t)n * H_DIM * WROW;
    const int hr0 = tid >> 4, wi = tid & 15;     // task 0: t = tid
    const int ra = r0 - PADR + hr0;
    uint32_t w0 = 0, w1 = 0;
    if (ra >= 0 && ra < H_DIM) w0 = bmn[ra * WROW + wi];
    const int hr1 = hr0 + 32;                    // task 1: t = tid + 512 (tid < 96)
    const int rb = r0 - PADR + hr1;
    if (tid < 96 && rb >= 0 && rb < H_DIM) w1 = bmn[rb * WROW + wi];

    // ---- pred loads issued early: outstanding across staging+barrier+popcounts
    const size_t img = (size_t)n * H_DIM * W_DIM;
    const float* __restrict__ p0 = pred + img * 2 + (size_t)r0 * W_DIM + col;
    const float* __restrict__ p1 = p0 + (size_t)H_DIM * W_DIM;
    float x0[BAND], x1[BAND];
#pragma unroll
    for (int rr = 0; rr < BAND; ++rr) {
        x0[rr] = p0[rr * W_DIM];
        x1[rr] = p1[rr * W_DIM];
    }

    // ---- LDS writes (wait only on bitmap loads; pred stays in flight) ----
    if (tid < 2 * HALO) B[tid >> 1][(tid & 1) ? (WPR - 1) : 0] = 0u;
    B[hr0][1 + wi] = w0;
    if (tid < 96) B[hr1][1 + wi] = w1;
    __syncthreads();

    // ---- 31-bit window popcount helper (near-broadcast LDS reads) ----
    const int b = col + (32 - PADR);             // window start bit (word 0 = pad)
    const int q = b >> 5, s = b & 31;
    auto wpop = [&](int i) -> uint32_t {
        const uint32_t lo = B[i][q];
        const uint32_t hi = B[i][q + 1];
        return (uint32_t)((((uint64_t)hi << 32) | lo) >> s) & 0x7FFFFFFFu;
    };

    // ---- initial vertical window (halo rows 0..30) + center-bit mask ----
    uint32_t run = 0, mbits = 0;
#pragma unroll
    for (int i = 0; i < 31; ++i) {
        const uint32_t val = wpop(i);
        run += (uint32_t)__popc(val);
        if (i >= PADR && i < PADR + BAND)
            mbits |= ((val >> PADR) & 1u) << (i - PADR);  // center bit = window bit 15
    }

    // ---- register pin: x0/x1 must be materialized HERE (loads may not be
    // sunk into the loss loop; their latency is already hidden under phase B)
#pragma unroll
    for (int rr = 0; rr < BAND; ++rr) {
        asm volatile("" : "+v"(x0[rr]), "+v"(x1[rr]));
    }

    // ---- loss math ----
    const int cntw = min(col + PADR, W_DIM - 1) - max(col - PADR, 0) + 1;
    const float inv961 = 1.0f / 961.0f;
    float bce = 0.f, in0 = 0.f, in1 = 0.f, un0 = 0.f, un1 = 0.f;

#pragma unroll
    for (int rr = 0; rr < BAND; ++rr) {
        const int r = r0 + rr;
        const int cnth = min(r + PADR, H_DIM - 1) - max(r - PADR, 0) + 1;
        const float cnt = (float)(cnth * cntw);
        const float m1 = (float)((mbits >> rr) & 1u);
        const float m0 = 1.0f - m1;
        const float V = (float)run;
        const float box1 = V * inv961;
        const float box0 = (cnt - V) * inv961;
        const float w1f = 1.0f + 5.0f * fabsf(box1 - m1);
        const float w0f = 1.0f + 5.0f * fabsf(box0 - m0);
        {   // channel 0
            const float x = x0[rr];
            const float t = __expf(-fabsf(x));
            const float inv = 1.0f / (1.0f + t);
            const float p = (x >= 0.f) ? inv : t * inv;
            bce += fmaxf(x, 0.f) - x * m0 + __logf(1.0f + t);
            in0 += p * m0 * w0f;
            un0 += (p + m0) * w0f;
        }
        {   // channel 1
            const float x = x1[rr];
            const float t = __expf(-fabsf(x));
            const float inv = 1.0f / (1.0f + t);
            const float p = (x >= 0.f) ? inv : t * inv;
            bce += fmaxf(x, 0.f) - x * m1 + __logf(1.0f + t);
            in1 += p * m1 * w1f;
            un1 += (p + m1) * w1f;
        }
        if (rr < BAND - 1)   // slide vertical window: recompute from LDS (no h[])
            run += (uint32_t)__popc(wpop(rr + 31)) - (uint32_t)__popc(wpop(rr));
    }

    // ---- block reduction: 5 values -> plain store to private slot ----
    __shared__ float red[8 * 5];
    const int lane = tid & 63, wv = tid >> 6;
    float v[5] = {bce, in0, in1, un0, un1};
#pragma unroll
    for (int k = 0; k < 5; ++k)
#pragma unroll
        for (int off = 32; off > 0; off >>= 1)
            v[k] += __shfl_down(v[k], off);
    if (lane == 0)
#pragma unroll
        for (int k = 0; k < 5; ++k) red[wv * 5 + k] = v[k];
    __syncthreads();
    if (tid == 0) {
        float s2[5];
#pragma unroll
        for (int k = 0; k < 5; ++k) {
            s2[k] = red[k];
            for (int w2 = 1; w2 < 8; ++w2) s2[k] += red[w2 * 5 + k];
        }
        float* p = part + (size_t)(n * NBANDS + band) * 5;
#pragma unroll
        for (int k = 0; k < 5; ++k) p[k] = s2[k];
    }
}

// ---------------------------------------------------------------------------
// Finalize: reduce 1024 block-partials -> out[0]. One block.
// 16 threads per image; each accumulates 4 partial rows.
// ---------------------------------------------------------------------------
__global__ __launch_bounds__(256) void finalize_kernel(const float* __restrict__ part,
                                                       float* __restrict__ out) {
    const int tid = threadIdx.x;   // 0..255
    const int n = tid >> 4;        // image
    const int i = tid & 15;
    float bce = 0.f, in0 = 0.f, in1 = 0.f, un0 = 0.f, un1 = 0.f;
#pragma unroll
    for (int j = 0; j < 4; ++j) {
        const float* p = part + (size_t)(n * NBANDS + j * 16 + i) * 5;
        bce += p[0]; in0 += p[1]; in1 += p[2]; un0 += p[3]; un1 += p[4];
    }
#pragma unroll
    for (int off = 8; off > 0; off >>= 1) {
        bce += __shfl_xor(bce, off, 16);
        in0 += __shfl_xor(in0, off, 16);
        in1 += __shfl_xor(in1, off, 16);
        un0 += __shfl_xor(un0, off, 16);
        un1 += __shfl_xor(un1, off, 16);
    }
    __shared__ float fb[16], fw[16];
    if (i == 0) {
        fb[n] = bce;
        fw[n] = (1.0f - (in0 + 1.0f) / (un0 - in0 + 1.0f)) +
                (1.0f - (in1 + 1.0f) / (un1 - in1 + 1.0f));
    }
    __syncthreads();
    if (tid == 0) {
        float sb = 0.f, sw = 0.f;
#pragma unroll
        for (int k = 0; k < 16; ++k) { sb += fb[k]; sw += fw[k]; }
        out[0] = sb / 8388608.0f + sw * (1.0f / 32.0f);  // 16*2*512*512 ; 32 (n,c) pairs
    }
}

extern "C" void kernel_launch(void* const* d_in, const int* in_sizes, int n_in,
                              void* d_out, int out_size, void* d_ws, size_t ws_size,
                              hipStream_t stream) {
    const float* pred = (const float*)d_in[0];
    const int* target = (const int*)d_in[1];
    float* part = (float*)d_ws;
    uint32_t* bm = (uint32_t*)((char*)d_ws + 32768);

    bitmap_kernel<<<2048, 256, 0, stream>>>((const int4*)target, bm);
    dim3 grid(NBANDS, N_IMG);
    mega_kernel<<<grid, 512, 0, stream>>>(bm, pred, part);
    finalize_kernel<<<1, 256, 0, stream>>>(part, (float*)d_out);
}

// Round 7
// 24.674 us; speedup vs baseline: 2.0249x; 1.0864x over previous
//
#include <hip/hip_runtime.h>
#include <stdint.h>

#define N_IMG 16
#define H_DIM 512
#define W_DIM 512
#define PADR 15
#define BAND 8                  // output rows per mega block
#define HALO (BAND + 2 * PADR)  // 38 staged bitmap rows
#define WPR 18                  // 32-bit words per bitmap row: 1 pad + 16 data + 1 pad
#define NBANDS (H_DIM / BAND)   // 64
#define WROW (W_DIM / 32)       // 16 data words per row

// ws layout (poison-safe: every word written before read, every launch):
//   part @ 0      : 1024 blocks * 5 f32  [bce,in0,in1,un0,un1]
//   bm   @ 32 KiB : uint32 bm[N][512][16]  (bit c&31 of word c>>5 = target==1)

// ---------------------------------------------------------------------------
// Stage 1: target -> bit-plane. int4 x2 per thread (8 elems), words assembled
// with 2 shfl_xor OR-merges. 2048 blocks x 256 threads; ~HBM-bound (16.8 MB).
// ---------------------------------------------------------------------------
__global__ __launch_bounds__(256) void bitmap_kernel(const int4* __restrict__ tg4,
                                                     uint32_t* __restrict__ bm) {
    const int tid = threadIdx.x;
    const size_t t = (size_t)blockIdx.x * 256 + tid;   // global thread, 8 ints each
    const int4 a = tg4[t * 2];
    const int4 b = tg4[t * 2 + 1];
    uint32_t by = (uint32_t)(a.x == 1) | ((uint32_t)(a.y == 1) << 1) |
                  ((uint32_t)(a.z == 1) << 2) | ((uint32_t)(a.w == 1) << 3) |
                  ((uint32_t)(b.x == 1) << 4) | ((uint32_t)(b.y == 1) << 5) |
                  ((uint32_t)(b.z == 1) << 6) | ((uint32_t)(b.w == 1) << 7);
    uint32_t w = by << (8 * (tid & 3));
    w |= __shfl_xor(w, 1);
    w |= __shfl_xor(w, 2);
    if ((tid & 3) == 0) bm[t >> 2] = w;
}

// ---------------------------------------------------------------------------
// Stage 2: fused 31x31 box-sum (popcount over bit-plane) + elementwise loss.
// Block = 512 threads (one per col) x 8 output rows. 1024 blocks -> 4/CU.
// All 38 horizontal window popcounts computed ONCE in the init loop; the 14
// needed by the vertical slide are register-pinned (R5 lesson: pins stop the
// allocator from sinking/recomputing). Sigmoid via v_rcp (no div sequence).
// ---------------------------------------------------------------------------
__global__ __launch_bounds__(512, 8) void mega_kernel(const uint32_t* __restrict__ bm,
                                                      const float* __restrict__ pred,
                                                      float* __restrict__ part) {
    __shared__ uint32_t B[HALO][WPR];
    const int tid = threadIdx.x;                 // = col
    const int band = blockIdx.x;                 // 0..63
    const int n = blockIdx.y;
    const int r0 = band * BAND;
    const int col = tid;

    // ---- bitmap halo staging: 38 rows x 16 words = 608 loads, 2 per thread ----
    const uint32_t* __restrict__ bmn = bm + (size_t)n * H_DIM * WROW;
    const int hr0 = tid >> 4, wi = tid & 15;     // task 0: t = tid
    const int ra = r0 - PADR + hr0;
    uint32_t w0 = 0, w1 = 0;
    if (ra >= 0 && ra < H_DIM) w0 = bmn[ra * WROW + wi];
    const int hr1 = hr0 + 32;                    // task 1: t = tid + 512 (tid < 96)
    const int rb = r0 - PADR + hr1;
    if (tid < 96 && rb >= 0 && rb < H_DIM) w1 = bmn[rb * WROW + wi];

    // ---- pred loads issued early: outstanding across staging+barrier+popcounts
    const size_t img = (size_t)n * H_DIM * W_DIM;
    const float* __restrict__ p0 = pred + img * 2 + (size_t)r0 * W_DIM + col;
    const float* __restrict__ p1 = p0 + (size_t)H_DIM * W_DIM;
    float x0[BAND], x1[BAND];
#pragma unroll
    for (int rr = 0; rr < BAND; ++rr) {
        x0[rr] = p0[rr * W_DIM];
        x1[rr] = p1[rr * W_DIM];
    }

    // ---- LDS writes (wait only on bitmap loads; pred stays in flight) ----
    if (tid < 2 * HALO) B[tid >> 1][(tid & 1) ? (WPR - 1) : 0] = 0u;
    B[hr0][1 + wi] = w0;
    if (tid < 96) B[hr1][1 + wi] = w1;
    __syncthreads();

    // ---- phase B: ALL 38 horizontal 31-bit window popcounts, one pass ----
    const int b = col + (32 - PADR);             // window start bit (word 0 = pad)
    const int q = b >> 5, s = b & 31;
    uint32_t run = 0, mbits = 0;
    uint32_t hlo[7], hhi[7];                     // h[0..6], h[31..37] for the slide
#pragma unroll
    for (int i = 0; i < HALO; ++i) {
        const uint32_t lo = B[i][q];
        const uint32_t hi = B[i][q + 1];
        const uint32_t val =
            (uint32_t)((((uint64_t)hi << 32) | lo) >> s) & 0x7FFFFFFFu;  // v_alignbit
        const uint32_t hv = (uint32_t)__popc(val);
        if (i < 31) run += hv;                   // initial vertical window
        if (i < 7) hlo[i] = hv;
        if (i >= 31) hhi[i - 31] = hv;
        if (i >= PADR && i < PADR + BAND)
            mbits |= ((val >> PADR) & 1u) << (i - PADR);  // center bit = window bit 15
    }

    // ---- register pin: x0/x1 and slide h-values must be materialized HERE
#pragma unroll
    for (int rr = 0; rr < BAND; ++rr) asm volatile("" : "+v"(x0[rr]), "+v"(x1[rr]));
#pragma unroll
    for (int i = 0; i < 7; ++i) asm volatile("" : "+v"(hlo[i]), "+v"(hhi[i]));

    // ---- loss math ----
    const int cntw = min(col + PADR, W_DIM - 1) - max(col - PADR, 0) + 1;
    const float inv961 = 1.0f / 961.0f;
    float bce = 0.f, in0 = 0.f, in1 = 0.f, un0 = 0.f, un1 = 0.f;

#pragma unroll
    for (int rr = 0; rr < BAND; ++rr) {
        const int r = r0 + rr;
        const int cnth = min(r + PADR, H_DIM - 1) - max(r - PADR, 0) + 1;
        const float cnt = (float)(cnth * cntw);
        const float m1 = (float)((mbits >> rr) & 1u);
        const float m0 = 1.0f - m1;
        const float V = (float)run;
        const float box1 = V * inv961;
        const float box0 = (cnt - V) * inv961;
        const float w1f = 1.0f + 5.0f * fabsf(box1 - m1);
        const float w0f = 1.0f + 5.0f * fabsf(box0 - m0);
        {   // channel 0
            const float x = x0[rr];
            const float t = __expf(-fabsf(x));
            const float inv = __builtin_amdgcn_rcpf(1.0f + t);   // v_rcp_f32
            const float p = (x >= 0.f) ? inv : t * inv;
            bce += fmaxf(x, 0.f) - x * m0 + __logf(1.0f + t);
            in0 += p * m0 * w0f;
            un0 += (p + m0) * w0f;
        }
        {   // channel 1
            const float x = x1[rr];
            const float t = __expf(-fabsf(x));
            const float inv = __builtin_amdgcn_rcpf(1.0f + t);
            const float p = (x >= 0.f) ? inv : t * inv;
            bce += fmaxf(x, 0.f) - x * m1 + __logf(1.0f + t);
            in1 += p * m1 * w1f;
            un1 += (p + m1) * w1f;
        }
        if (rr < BAND - 1)   // slide vertical window: 2 int ops, no LDS
            run += hhi[rr] - hlo[rr];
    }

    // ---- block reduction: 5 values -> plain store to private slot ----
    __shared__ float red[8 * 5];
    const int lane = tid & 63, wv = tid >> 6;
    float v[5] = {bce, in0, in1, un0, un1};
#pragma unroll
    for (int k = 0; k < 5; ++k)
#pragma unroll
        for (int off = 32; off > 0; off >>= 1)
            v[k] += __shfl_down(v[k], off);
    if (lane == 0)
#pragma unroll
        for (int k = 0; k < 5; ++k) red[wv * 5 + k] = v[k];
    __syncthreads();
    if (tid == 0) {
        float s2[5];
#pragma unroll
        for (int k = 0; k < 5; ++k) {
            s2[k] = red[k];
            for (int w2 = 1; w2 < 8; ++w2) s2[k] += red[w2 * 5 + k];
        }
        float* p = part + (size_t)(n * NBANDS + band) * 5;
#pragma unroll
        for (int k = 0; k < 5; ++k) p[k] = s2[k];
    }
}

// ---------------------------------------------------------------------------
// Finalize: reduce 1024 block-partials -> out[0]. One block.
// 16 threads per image; each accumulates 4 partial rows.
// ---------------------------------------------------------------------------
__global__ __launch_bounds__(256) void finalize_kernel(const float* __restrict__ part,
                                                       float* __restrict__ out) {
    const int tid = threadIdx.x;   // 0..255
    const int n = tid >> 4;        // image
    const int i = tid & 15;
    float bce = 0.f, in0 = 0.f, in1 = 0.f, un0 = 0.f, un1 = 0.f;
#pragma unroll
    for (int j = 0; j < 4; ++j) {
        const float* p = part + (size_t)(n * NBANDS + j * 16 + i) * 5;
        bce += p[0]; in0 += p[1]; in1 += p[2]; un0 += p[3]; un1 += p[4];
    }
#pragma unroll
    for (int off = 8; off > 0; off >>= 1) {
        bce += __shfl_xor(bce, off, 16);
        in0 += __shfl_xor(in0, off, 16);
        in1 += __shfl_xor(in1, off, 16);
        un0 += __shfl_xor(un0, off, 16);
        un1 += __shfl_xor(un1, off, 16);
    }
    __shared__ float fb[16], fw[16];
    if (i == 0) {
        fb[n] = bce;
        fw[n] = (1.0f - (in0 + 1.0f) / (un0 - in0 + 1.0f)) +
                (1.0f - (in1 + 1.0f) / (un1 - in1 + 1.0f));
    }
    __syncthreads();
    if (tid == 0) {
        float sb = 0.f, sw = 0.f;
#pragma unroll
        for (int k = 0; k < 16; ++k) { sb += fb[k]; sw += fw[k]; }
        out[0] = sb / 8388608.0f + sw * (1.0f / 32.0f);  // 16*2*512*512 ; 32 (n,c) pairs
    }
}

extern "C" void kernel_launch(void* const* d_in, const int* in_sizes, int n_in,
                              void* d_out, int out_size, void* d_ws, size_t ws_size,
                              hipStream_t stream) {
    const float* pred = (const float*)d_in[0];
    const int* target = (const int*)d_in[1];
    float* part = (float*)d_ws;
    uint32_t* bm = (uint32_t*)((char*)d_ws + 32768);

    bitmap_kernel<<<2048, 256, 0, stream>>>((const int4*)target, bm);
    dim3 grid(NBANDS, N_IMG);
    mega_kernel<<<grid, 512, 0, stream>>>(bm, pred, part);
    finalize_kernel<<<1, 256, 0, stream>>>(part, (float*)d_out);
}